// Round 13
// baseline (32.090 us; speedup 1.0000x reference)
//
#include <hip/hip_runtime.h>
#include <hip/hip_bf16.h>
#include <math.h>

// Problem constants
#define Bn    8
#define Sn    8
#define COUTc 128
#define PWc   73728
#define Pc    73856
#define WOc   30
#define NPIX  900      // 30*30 per (b,s)
#define GPIX  7200     // B*NPIX per s
#define NSTEP 9        // r=(ky,kx) taps; conv does 18 half-steps of 32 ci
#define TILE  128      // pixels per block
#define NT2   57       // ceil(7200/128)
#define NSLOT 129      // 128 W-prep blocks + 1 bias block

typedef __bf16 bf16;
typedef bf16  bf16x8 __attribute__((ext_vector_type(8)));
typedef float f32x4v __attribute__((ext_vector_type(4)));
typedef float f32x16 __attribute__((ext_vector_type(16)));

__device__ __forceinline__ float softplus_f(float x) {
    return fmaxf(x, 0.f) + log1pf(expf(-fabsf(x)));
}

__device__ __forceinline__ unsigned int pack2(float a, float b) {
    unsigned short ua = __builtin_bit_cast(unsigned short, (bf16)a);
    unsigned short ub = __builtin_bit_cast(unsigned short, (bf16)b);
    return ((unsigned int)ub << 16) | (unsigned int)ua;
}

// global->LDS direct copy, 16B per lane. LDS dest = wave-uniform base
// (+ implicit lane*16); global src is per-lane.
__device__ __forceinline__ void gl16(const void* g, void* l) {
    typedef __attribute__((address_space(1))) void gvoid;
    typedef __attribute__((address_space(3))) void lvoid;
    __builtin_amdgcn_global_load_lds((gvoid*)g, (lvoid*)l, 16, 0, 0);
}

// ---------------------------------------------------------------------------
// Kernel 1 (fused) — unchanged from R12 (passed, at HBM floor):
//  blocks 0..511  : xcast  x fp32 NCHW -> xt bf16 channels-last [img][yx][ci]
//  blocks 512..639: W sampling into swizzled per-(s,r) 16 KB pages
//  block  640     : bias sampling
//  wimg page (s,r) byte: co*128 + ((ci>>3)^(co&7))*16 + (ci&7)*2.
// ---------------------------------------------------------------------------
__global__ __launch_bounds__(256) void prep_all(
        const float* __restrict__ xg, const float* __restrict__ e,
        const float* __restrict__ mu_w, const float* __restrict__ rho_w,
        const float* __restrict__ mu_b, const float* __restrict__ rho_b,
        bf16* __restrict__ xt, bf16* __restrict__ wimg,
        float* __restrict__ bq, float* __restrict__ slots) {
    const int bid = blockIdx.x;
    const int t   = threadIdx.x;

    if (bid < 512) {  // ---- xcast: thread = (oct, 4 consecutive pixels)
        const int img = bid >> 3;
        const int oct = t & 7;
        const int p0  = ((bid & 7) * 32 + (t >> 3)) * 4;
        const float* src = xg + ((size_t)img << 16) + (size_t)(oct * 8) * 1024 + p0;
        f32x4v v[8];
        #pragma unroll
        for (int j = 0; j < 8; ++j)
            v[j] = *reinterpret_cast<const f32x4v*>(src + (size_t)j * 1024);
        char* dstB = (char*)xt + (((size_t)(img << 10) + p0) << 7) + (oct << 4);
        #pragma unroll
        for (int i = 0; i < 4; ++i) {
            uint4 pk;
            pk.x = pack2(v[0][i], v[1][i]);
            pk.y = pack2(v[2][i], v[3][i]);
            pk.z = pack2(v[4][i], v[5][i]);
            pk.w = pack2(v[6][i], v[7][i]);
            *reinterpret_cast<uint4*>(dstB + (size_t)i * 128) = pk;
        }
        return;
    }

    float ls = 0.f, sq = 0.f;
    if (bid < 640) {  // ---- W prep: block = (s-group, chunk); 2 samples each
        const int rb    = bid - 512;
        const int sg2   = rb >> 5;
        const int chunk = rb & 31;
        const int gidx  = chunk * 256 + t;
        const int co    = gidx >> 6;
        const int ci    = gidx & 63;
        const int p0    = co * 576 + ci * 9;
        float mu[9], sg[9];
        #pragma unroll
        for (int r = 0; r < 9; ++r) {
            mu[r] = mu_w[p0 + r];
            sg[r] = softplus_f(rho_w[p0 + r]);
        }
        if (sg2 == 0) {
            #pragma unroll
            for (int r = 0; r < 9; ++r) ls += logf(sg[r]);
        }
        const int dstp = (co << 6) + (((ci >> 3) ^ (co & 7)) << 3) + (ci & 7);
        #pragma unroll
        for (int si = 0; si < 2; ++si) {
            const int s = sg2 * 2 + si;
            const float* es = e + s * Pc + p0;
            #pragma unroll
            for (int r = 0; r < 9; ++r) {
                float wv = fmaf(sg[r], es[r], mu[r]);
                wimg[((s * NSTEP + r) << 13) + dstp] = (bf16)wv;
                sq += wv * wv;
            }
        }
    } else {          // ---- bias prep (bid == 640)
        if (t < COUTc) {
            float sig = softplus_f(rho_b[t]);
            ls = logf(sig);
            float mu = mu_b[t];
            #pragma unroll
            for (int s = 0; s < Sn; ++s) {
                float bv = fmaf(sig, e[s * Pc + PWc + t], mu);
                bq[s * COUTc + t] = bv;
                sq += bv * bv;
            }
        }
    }

    #pragma unroll
    for (int off = 32; off > 0; off >>= 1) {
        ls += __shfl_down(ls, off);
        sq += __shfl_down(sq, off);
    }
    __shared__ float sls[4], ssq[4];
    const int lane = t & 63, wd = t >> 6;
    if (lane == 0) { sls[wd] = ls; ssq[wd] = sq; }
    __syncthreads();
    if (t == 0) {
        slots[2 * (bid - 512)]     = sls[0] + sls[1] + sls[2] + sls[3];
        slots[2 * (bid - 512) + 1] = ssq[0] + ssq[1] + ssq[2] + ssq[3];
    }
}

// ---------------------------------------------------------------------------
// Kernel 2: implicit-GEMM conv — R5 schedule at BK=32 (18 half-steps).
// Per step stage 8 KB W + 8 KB X (4 gl16/wave), depth-2 counted vmcnt(4),
// 2 raw barriers. LDS = 2x8 + 2x8 = 32 KB -> 4-5 blocks/CU (2-2.5x R5 TLP).
// LDS rows are 64 B (4 slots); swizzle slot = koct ^ ((row>>2)&3), inverse
// folded into per-lane GLOBAL sources (wimg/xt layouts unchanged).
// s = bid&7 XCD-affine. KL finalize (wave-parallel) in block 0.
// ---------------------------------------------------------------------------
__global__ __launch_bounds__(256) void conv_mfma(
        const bf16* __restrict__ xt, const bf16* __restrict__ wimg,
        const float* __restrict__ bq, const float* __restrict__ slots,
        float* __restrict__ out, float* __restrict__ klout) {
    const int bid  = blockIdx.x;
    const int s    = bid & 7;
    const int tile = bid >> 3;
    const int t    = threadIdx.x;
    const int lane = t & 63;
    const int w    = t >> 6;
    const int wr   = w >> 1;     // co half (0/1)
    const int wc   = w & 1;      // pix half (0/1)
    const int hi   = lane >> 5;
    const int lo   = lane & 31;

    __shared__ bf16 Wbuf[2][4096];   // 2 x 8 KB  [co 0..127][4 swz slots x 8ci]
    __shared__ bf16 Xbuf[2][4096];   // 2 x 8 KB  [pix 0..127][4 swz slots x 8ci]

    // ---- staging geometry: lane covers (row = q*16 + (lane>>2), slot=lane&3)
    const int srow  = lane >> 2;          // row within 16-row gl16 group
    const int sslot = lane & 3;
    const int rb23  = (lane >> 4) & 3;    // row bits 2-3 (= (row>>2)&3)

    // W sources (h = ci-half). page slot = oct8 ^ (co&7); derived:
    //   byte = co*128 + (sslot ^ rb23 ^ (co&3))*16 + ((h ^ ((co>>2)&1))*64
    const char* wsp[2][2];   // [h][q]
    {
        const int lowslot = sslot ^ rb23 ^ (srow & 3);
        const char* base = (const char*)wimg + ((size_t)(s * NSTEP) << 14);
        #pragma unroll
        for (int q = 0; q < 2; ++q) {
            int co = w * 32 + q * 16 + srow;
            const char* p0 = base + co * 128 + lowslot * 16;
            wsp[0][q] = p0 + (((lane >> 4) & 1) << 6);
            wsp[1][q] = p0 + ((1 ^ ((lane >> 4) & 1)) << 6);
        }
    }

    // X sources: logical oct low2 = sslot ^ rb23; h adds +64, tap adds dyx*128
    const char* xsp[2];
    #pragma unroll
    for (int q = 0; q < 2; ++q) {
        int pix = w * 32 + q * 16 + srow;
        int g   = tile * TILE + pix;
        if (g >= GPIX) g = GPIX - 1;      // clamp; garbage cols discarded
        int b2 = g / NPIX, rr = g - b2 * NPIX, oy = rr / WOc, ox = rr - oy * WOc;
        xsp[q] = (const char*)xt
            + ((((size_t)(b2 * Sn + s) << 10) + oy * 32 + ox) << 7)
            + ((sslot ^ rb23) << 4);
    }

    f32x16 acc[2][2];
    #pragma unroll
    for (int i = 0; i < 2; ++i)
        #pragma unroll
        for (int j = 0; j < 2; ++j)
            #pragma unroll
            for (int k = 0; k < 16; ++k)
                acc[i][j][k] = 0.f;

    #define STAGE(stepc, b)                                                  \
    {                                                                        \
        constexpr int r_ = (stepc) >> 1;                                     \
        constexpr int h_ = (stepc) & 1;                                      \
        constexpr size_t pg_ = (size_t)r_ << 14;                             \
        constexpr int ro_ = ((r_ / 3) * 32 + (r_ % 3)) * 128 + h_ * 64;      \
        char* wl_ = (char*)(&Wbuf[(b)][0]) + (w << 11);                      \
        char* xl_ = (char*)(&Xbuf[(b)][0]) + (w << 11);                      \
        gl16(wsp[h_][0] + pg_, wl_);                                         \
        gl16(wsp[h_][1] + pg_, wl_ + 1024);                                  \
        gl16(xsp[0] + ro_, xl_);                                             \
        gl16(xsp[1] + ro_, xl_ + 1024);                                      \
    }

    #define COMPUTE(b)                                                       \
    {                                                                        \
        const bf16* Wl_ = &Wbuf[(b)][0];                                     \
        const bf16* Xl_ = &Xbuf[(b)][0];                                     \
        _Pragma("unroll")                                                    \
        for (int kc = 0; kc < 2; ++kc) {                                     \
            const int slot_ = (((kc << 1) + hi) ^ ((lo >> 2) & 3)) << 3;     \
            bf16x8 af0 = *reinterpret_cast<const bf16x8*>(                   \
                Wl_ + ((wr * 64 + lo) << 5) + slot_);                        \
            bf16x8 af1 = *reinterpret_cast<const bf16x8*>(                   \
                Wl_ + ((wr * 64 + 32 + lo) << 5) + slot_);                   \
            bf16x8 bf0 = *reinterpret_cast<const bf16x8*>(                   \
                Xl_ + ((wc * 64 + lo) << 5) + slot_);                        \
            bf16x8 bf1 = *reinterpret_cast<const bf16x8*>(                   \
                Xl_ + ((wc * 64 + 32 + lo) << 5) + slot_);                   \
            acc[0][0] = __builtin_amdgcn_mfma_f32_32x32x16_bf16(af0, bf0, acc[0][0], 0, 0, 0); \
            acc[0][1] = __builtin_amdgcn_mfma_f32_32x32x16_bf16(af0, bf1, acc[0][1], 0, 0, 0); \
            acc[1][0] = __builtin_amdgcn_mfma_f32_32x32x16_bf16(af1, bf0, acc[1][0], 0, 0, 0); \
            acc[1][1] = __builtin_amdgcn_mfma_f32_32x32x16_bf16(af1, bf1, acc[1][1], 0, 0, 0); \
        }                                                                    \
    }

    // prologue: two stages in flight
    STAGE(0, 0);
    STAGE(1, 1);

    #define ITER(tt)                                                         \
        asm volatile("s_waitcnt vmcnt(4)" ::: "memory");                     \
        __builtin_amdgcn_s_barrier();                                        \
        __builtin_amdgcn_sched_barrier(0);                                   \
        COMPUTE((tt) & 1);                                                   \
        __builtin_amdgcn_sched_barrier(0);                                   \
        __builtin_amdgcn_s_barrier();                                        \
        STAGE((tt) + 2, (tt) & 1);

    ITER(0)  ITER(1)  ITER(2)  ITER(3)
    ITER(4)  ITER(5)  ITER(6)  ITER(7)
    ITER(8)  ITER(9)  ITER(10) ITER(11)
    ITER(12) ITER(13) ITER(14) ITER(15)
    // step 16 (buf 0): no further stage
    asm volatile("s_waitcnt vmcnt(4)" ::: "memory");
    __builtin_amdgcn_s_barrier();
    __builtin_amdgcn_sched_barrier(0);
    COMPUTE(0);
    // step 17 (buf 1): final, drain
    asm volatile("s_waitcnt vmcnt(0)" ::: "memory");
    __builtin_amdgcn_s_barrier();
    __builtin_amdgcn_sched_barrier(0);
    COMPUTE(1);

    #undef ITER
    #undef COMPUTE
    #undef STAGE

    // ---- epilogue: 32x32 C/D: col(pix)=lane&31, row(co)=(reg&3)+8*(reg>>2)+4*hi
    #pragma unroll
    for (int ti = 0; ti < 2; ++ti) {
        float bs[16];
        #pragma unroll
        for (int reg = 0; reg < 16; ++reg) {
            int co = wr * 64 + ti * 32 + (reg & 3) + 8 * (reg >> 2) + 4 * hi;
            bs[reg] = bq[s * COUTc + co];
        }
        #pragma unroll
        for (int tj = 0; tj < 2; ++tj) {
            int gg = tile * TILE + wc * 64 + tj * 32 + lo;
            if (gg >= GPIX) continue;
            int b2 = gg / NPIX;
            int r2 = gg - b2 * NPIX;
            float* ob = out + (size_t)(b2 * Sn + s) * (COUTc * NPIX) + r2;
            #pragma unroll
            for (int reg = 0; reg < 16; ++reg) {
                int co = wr * 64 + ti * 32 + (reg & 3) + 8 * (reg >> 2) + 4 * hi;
                ob[co * NPIX] = acc[ti][tj][reg] + bs[reg];
            }
        }
    }

    // ---- KL finalize (block 0, wave 0, lane-parallel over NSLOT slots)
    if (bid == 0 && w == 0) {
        float ls = 0.f, sq = 0.f;
        for (int i2 = lane; i2 < NSLOT; i2 += 64) {
            ls += slots[2 * i2];
            sq += slots[2 * i2 + 1];
        }
        #pragma unroll
        for (int off = 32; off > 0; off >>= 1) {
            ls += __shfl_down(ls, off);
            sq += __shfl_down(sq, off);
        }
        if (lane == 0)
            *klout = -ls + 0.91893853320467274f * (float)Pc + 0.5f * sq;
    }
}

// ---------------------------------------------------------------------------
extern "C" void kernel_launch(void* const* d_in, const int* in_sizes, int n_in,
                              void* d_out, int out_size, void* d_ws, size_t ws_size,
                              hipStream_t stream) {
    const float* x     = (const float*)d_in[0];
    const float* e     = (const float*)d_in[1];
    const float* mu_w  = (const float*)d_in[2];
    const float* rho_w = (const float*)d_in[3];
    const float* mu_b  = (const float*)d_in[4];
    const float* rho_b = (const float*)d_in[5];
    float* out = (float*)d_out;

    // workspace layout
    bf16*  wimg  = (bf16*)d_ws;                         // 1,179,648 B
    float* bq    = (float*)((char*)d_ws + 1179648);     // 4,096 B
    float* slots = (float*)((char*)d_ws + 1183744);     // 1,032 B (pad to 4K)
    bf16*  xt    = (bf16*)((char*)d_ws + 1187840);      // 8,388,608 B

    prep_all<<<dim3(641), dim3(256), 0, stream>>>(
        x, e, mu_w, rho_w, mu_b, rho_b, xt, wimg, bq, slots);

    conv_mfma<<<dim3(NT2 * Sn), dim3(256), 0, stream>>>(
        xt, wimg, bq, slots, out, out + (out_size - 1));
}